// Round 15
// baseline (47.187 us; speedup 1.0000x reference)
//
#include <hip/hip_runtime.h>
#include <hip/hip_fp16.h>

// Unsharp-mask: out = img + param * (img - gaussblur25(img)), param = 5*(tanh(f[b,0])*.5+.5)
// img: (16,3,512,512) fp32. Output: [out (12582912 fp32)] ++ [param (16 fp32)].
//
// R15: R14 in-place pipeline (stage f16 -> dot2 H -> in-place writeback ->
// f32 V + epilogue) made a 4-tile-deep software pipeline per block (T14):
// each block owns 4 z-planes; next tile's stage loads are issued into
// registers BEFORE the current tile's H/V compute, and written to LDS after
// V's barrier. HBM traffic now overlaps VALU phases via ILP (R14 showed
// extra TLP/occupancy does not buy overlap). Grid 8x8x12 = 3 blocks/CU.

#define RADIUS 12
#define KS     25
#define TILE   64
#define PT     (TILE + 2 * RADIUS)   // 88
#define TA_LD  104                   // f16 row stride: 208B (16B-aligned)
#define IMG_W  512
#define IMG_H  512
#define PLANE  (IMG_W * IMG_H)
#define NPLANE 48
#define ZPB    4                     // z-planes per block

#define N_STAGE (PT * 11)            // 968 8px slots
#define N_H     (PT * (TILE / 8))    // 704 8-output slots

// Normalized 25-tap Gaussian, sigma=5
__device__ __constant__ float GW[KS] = {
    0.00453456f, 0.00718308f, 0.01093238f, 0.01598625f, 0.02245983f,
    0.03031760f, 0.03931982f, 0.04899550f, 0.05865827f, 0.06747307f,
    0.07456928f, 0.07918039f, 0.08077993f, 0.07918039f, 0.07456928f,
    0.06747307f, 0.05865827f, 0.04899550f, 0.03931982f, 0.03031760f,
    0.02245983f, 0.01598625f, 0.01093238f, 0.00718308f, 0.00453456f
};

__device__ __forceinline__ int reflect512(int i) {
    i = (i < 0) ? -i : i;
    return (i >= 512) ? (1022 - i) : i;
}

typedef _Float16 h2_t __attribute__((ext_vector_type(2)));

__device__ __forceinline__ unsigned h2u(__half2 h) {
    union { __half2 h; unsigned u; } x; x.h = h; return x.u;
}
__device__ __forceinline__ float u_lo(unsigned u) {
    union { unsigned u; __half2 h; } x; x.u = u;
    return __half2float(__low2half(x.h));
}
__device__ __forceinline__ float u_hi(unsigned u) {
    union { unsigned u; __half2 h; } x; x.u = u;
    return __half2float(__high2half(x.h));
}

#if __has_builtin(__builtin_amdgcn_fdot2)
__device__ __forceinline__ float fdot2u(unsigned a, unsigned b, float c) {
    union { unsigned u; h2_t h; } ua, ub;
    ua.u = a; ub.u = b;
    return __builtin_amdgcn_fdot2(ua.h, ub.h, c, false);
}
#else
__device__ __forceinline__ float fdot2u(unsigned a, unsigned b, float c) {
    return c + u_lo(a) * u_lo(b) + u_hi(a) * u_hi(b);
}
#endif

// Issue the 8 staging float4 loads for one tile into registers (no LDS write).
__device__ __forceinline__ void stage_issue(
    const float* __restrict__ src, int tid, int tx0, int ty0, bool xedge,
    float4* pva, float4* pvb)
{
#pragma unroll
    for (int it = 0; it < 4; ++it) {
        const int li = tid + it * 256;
        if (it < 3 || li < N_STAGE) {
            const int py = li / 11, s = li - py * 11;
            const int gy = reflect512(ty0 - RADIUS + py);
            const float* __restrict__ rowp = src + (size_t)gy * IMG_W;
            const int gx = tx0 - RADIUS + s * 8;
            if (!xedge) {
                pva[it] = *(const float4*)(rowp + gx);
                pvb[it] = *(const float4*)(rowp + gx + 4);
            } else {
                float4 va, vb;
                va.x = rowp[reflect512(gx)];     va.y = rowp[reflect512(gx + 1)];
                va.z = rowp[reflect512(gx + 2)]; va.w = rowp[reflect512(gx + 3)];
                vb.x = rowp[reflect512(gx + 4)]; vb.y = rowp[reflect512(gx + 5)];
                vb.z = rowp[reflect512(gx + 6)]; vb.w = rowp[reflect512(gx + 7)];
                pva[it] = va; pvb[it] = vb;
            }
        }
    }
}

// Pack held registers to f16 and write the tile into LDS.
__device__ __forceinline__ void stage_write(
    __half (*tA)[TA_LD], int tid, const float4* pva, const float4* pvb)
{
#pragma unroll
    for (int it = 0; it < 4; ++it) {
        const int li = tid + it * 256;
        if (it < 3 || li < N_STAGE) {
            const int py = li / 11, s = li - py * 11;
            uint4 pk;
            pk.x = h2u(__floats2half2_rn(pva[it].x, pva[it].y));
            pk.y = h2u(__floats2half2_rn(pva[it].z, pva[it].w));
            pk.z = h2u(__floats2half2_rn(pvb[it].x, pvb[it].y));
            pk.w = h2u(__floats2half2_rn(pvb[it].z, pvb[it].w));
            *(uint4*)&tA[py][s * 8] = pk;
        }
    }
}

__device__ __forceinline__ uint4 h_slot(const __half (*tA)[TA_LD], int py, int g,
                                        const unsigned* W2, unsigned WE, unsigned WO) {
    const uint4 qa = *(const uint4*)&tA[py][g * 8];
    const uint4 qb = *(const uint4*)&tA[py][g * 8 + 8];
    const uint4 qc = *(const uint4*)&tA[py][g * 8 + 16];
    const uint4 qd = *(const uint4*)&tA[py][g * 8 + 24];

    unsigned P[16] = { qa.x, qa.y, qa.z, qa.w, qb.x, qb.y, qb.z, qb.w,
                       qc.x, qc.y, qc.z, qc.w, qd.x, qd.y, qd.z, qd.w };
    unsigned S[15];
#pragma unroll
    for (int i = 0; i < 15; ++i)
        S[i] = __builtin_amdgcn_alignbit(P[i + 1], P[i], 16);

    float acc[8];
#pragma unroll
    for (int h = 0; h < 4; ++h) {               // even outputs
        float a = 0.f;
#pragma unroll
        for (int m = 0; m < 12; ++m) a = fdot2u(P[h + m], W2[m], a);
        acc[2 * h] = fdot2u(P[h + 12], WE, a);
    }
#pragma unroll
    for (int h = 0; h < 4; ++h) {               // odd outputs
        float a = 0.f;
#pragma unroll
        for (int m = 0; m < 12; ++m) a = fdot2u(S[h + m], W2[m], a);
        acc[2 * h + 1] = fdot2u(P[h + 12], WO, a);
    }

    uint4 pk;
    pk.x = h2u(__floats2half2_rn(acc[0], acc[1]));
    pk.y = h2u(__floats2half2_rn(acc[2], acc[3]));
    pk.z = h2u(__floats2half2_rn(acc[4], acc[5]));
    pk.w = h2u(__floats2half2_rn(acc[6], acc[7]));
    return pk;
}

__global__ __launch_bounds__(256) void usm_fused_kernel(
    const float* __restrict__ img, const float* __restrict__ feat,
    float* __restrict__ out, float* __restrict__ out_param)
{
    __shared__ __half tileA[PT][TA_LD];   // 88x104 f16 = 17.9 KB

    const int tid = threadIdx.x;
    const int tx0 = blockIdx.x * TILE, ty0 = blockIdx.y * TILE;
    const int z0  = blockIdx.z * ZPB;
    const bool xedge = (blockIdx.x == 0) || (blockIdx.x == 7);

    unsigned W2[12];
#pragma unroll
    for (int m = 0; m < 12; ++m)
        W2[m] = h2u(__floats2half2_rn(GW[2 * m], GW[2 * m + 1]));
    const unsigned WE = h2u(__floats2half2_rn(GW[24], 0.f));
    const unsigned WO = h2u(__floats2half2_rn(0.f, GW[24]));

    const int tx4 = (tid & 15) * 4, ry0 = (tid >> 4) * 4;   // V-phase map

    // ---- prologue: stage tile z0 (not hidden; once per block) ----
    float4 pva[4], pvb[4];
    stage_issue(img + (size_t)z0 * PLANE, tid, tx0, ty0, xedge, pva, pvb);
    stage_write(tileA, tid, pva, pvb);
    __syncthreads();

    for (int t = 0; t < ZPB; ++t) {
        const int zc = z0 + t;
        const int b  = zc / 3;
        const float* __restrict__ src = img + (size_t)zc * PLANE;

        // ---- issue next tile's stage loads (fly during H+V) ----
        if (t + 1 < ZPB)
            stage_issue(src + PLANE, tid, tx0, ty0, xedge, pva, pvb);

        // ---- issue this tile's center loads (fly during H+V) ----
        float4 cv0 = *(const float4*)(src + (size_t)(ty0 + ry0 + 0) * IMG_W + tx0 + tx4);
        float4 cv1 = *(const float4*)(src + (size_t)(ty0 + ry0 + 1) * IMG_W + tx0 + tx4);
        float4 cv2 = *(const float4*)(src + (size_t)(ty0 + ry0 + 2) * IMG_W + tx0 + tx4);
        float4 cv3 = *(const float4*)(src + (size_t)(ty0 + ry0 + 3) * IMG_W + tx0 + tx4);

        const float param = (tanhf(feat[b * 8]) * 0.5f + 0.5f) * 5.0f;

        // ---- H compute from LDS (hold outputs in regs) ----
        const int li1 = tid + 256, li2 = tid + 512;
        const bool act2 = (li2 < N_H);                 // tid < 192
        uint4 h0 = h_slot(tileA, tid >> 3, tid & 7, W2, WE, WO);
        uint4 h1 = h_slot(tileA, li1 >> 3, li1 & 7, W2, WE, WO);
        uint4 h2w = act2 ? h_slot(tileA, li2 >> 3, li2 & 7, W2, WE, WO)
                         : make_uint4(0, 0, 0, 0);
        __syncthreads();

        // ---- in-place write-back into tileA cols 0..63 ----
        *(uint4*)&tileA[tid >> 3][(tid & 7) * 8] = h0;
        *(uint4*)&tileA[li1 >> 3][(li1 & 7) * 8] = h1;
        if (act2) *(uint4*)&tileA[li2 >> 3][(li2 & 7) * 8] = h2w;
        __syncthreads();

        // ---- V + epilogue: 4x4 micro-tile per thread ----
        float ax[4], ay[4], az[4], aw[4];
#pragma unroll
        for (int d = 0; d < 4; ++d) ax[d] = ay[d] = az[d] = aw[d] = 0.f;

#pragma unroll
        for (int k = 0; k < KS + 3; ++k) {            // 28 b64 row reads
            uint2 rd = *(const uint2*)&tileA[ry0 + k][tx4];
            const float c0 = u_lo(rd.x), c1 = u_hi(rd.x);
            const float c2 = u_lo(rd.y), c3 = u_hi(rd.y);
#pragma unroll
            for (int d = 0; d < 4; ++d) {
                const int kk = k - d;
                if (kk >= 0 && kk < KS) {
                    const float wk = GW[kk];
                    ax[d] += wk * c0; ay[d] += wk * c1;
                    az[d] += wk * c2; aw[d] += wk * c3;
                }
            }
        }

        float* __restrict__ dst = out + (size_t)zc * PLANE;
#pragma unroll
        for (int d = 0; d < 4; ++d) {
            const float4 v = (d == 0) ? cv0 : (d == 1) ? cv1 : (d == 2) ? cv2 : cv3;
            float4 o;
            o.x = v.x + param * (v.x - ax[d]);
            o.y = v.y + param * (v.y - ay[d]);
            o.z = v.z + param * (v.z - az[d]);
            o.w = v.w + param * (v.w - aw[d]);
            *(float4*)(dst + (size_t)(ty0 + ry0 + d) * IMG_W + tx0 + tx4) = o;
        }

        if (tid == 0 && blockIdx.x == 0 && blockIdx.y == 0 && (zc - b * 3) == 0)
            out_param[b] = param;

        // ---- land next tile into LDS ----
        if (t + 1 < ZPB) {
            __syncthreads();                          // all V reads done
            stage_write(tileA, tid, pva, pvb);        // waits its own vmcnt
            __syncthreads();
        }
    }
}

extern "C" void kernel_launch(void* const* d_in, const int* in_sizes, int n_in,
                              void* d_out, int out_size, void* d_ws, size_t ws_size,
                              hipStream_t stream) {
    const float* img  = (const float*)d_in[0];
    const float* feat = (const float*)d_in[1];
    float* out       = (float*)d_out;
    float* out_param = (float*)d_out + (size_t)NPLANE * PLANE;

    usm_fused_kernel<<<dim3(8, 8, NPLANE / ZPB), 256, 0, stream>>>(img, feat, out, out_param);
}

// Round 16
// 40.442 us; speedup vs baseline: 1.1668x; 1.1668x over previous
//
#include <hip/hip_runtime.h>
#include <hip/hip_fp16.h>

// Unsharp-mask: out = img + param * (img - gaussblur25(img)), param = 5*(tanh(f[b,0])*.5+.5)
// img: (16,3,512,512) fp32. Output: [out (12582912 fp32)] ++ [param (16 fp32)].
//
// R16 = R12 skeleton (stage f16 tileA -> dot2 H -> tmpB -> V + epilogue) with:
//  1) epilogue center read from tileA (f16, LDS) -- deletes 50 MB of global
//     epilogue loads (R8 fetched 46 MB with center-from-LDS vs 63 MB after),
//  2) V-phase in packed f16 (__hfma2 -> v_pk_fma_f16): ~200 pk-FMA vs 400,
//  3) bijective XCD swizzle: each XCD gets 6 contiguous z-planes -> halo
//     re-reads hit same-XCD L2.

#define RADIUS 12
#define KS     25
#define TILE   64
#define PT     (TILE + 2 * RADIUS)   // 88
#define TA_LD  104                   // tileA f16 stride: 208B
#define TB_LD  72                    // tmpB  f16 stride: 144B
#define IMG_W  512
#define IMG_H  512
#define PLANE  (IMG_W * IMG_H)
#define NPLANE 48

#define N_STAGE (PT * 11)            // 968 8px slots
#define N_H     (PT * (TILE / 8))    // 704 8-output slots

// Normalized 25-tap Gaussian, sigma=5
__device__ __constant__ float GW[KS] = {
    0.00453456f, 0.00718308f, 0.01093238f, 0.01598625f, 0.02245983f,
    0.03031760f, 0.03931982f, 0.04899550f, 0.05865827f, 0.06747307f,
    0.07456928f, 0.07918039f, 0.08077993f, 0.07918039f, 0.07456928f,
    0.06747307f, 0.05865827f, 0.04899550f, 0.03931982f, 0.03031760f,
    0.02245983f, 0.01598625f, 0.01093238f, 0.00718308f, 0.00453456f
};

__device__ __forceinline__ int reflect512(int i) {
    i = (i < 0) ? -i : i;
    return (i >= 512) ? (1022 - i) : i;
}

typedef _Float16 h2_t __attribute__((ext_vector_type(2)));

__device__ __forceinline__ unsigned h2u(__half2 h) {
    union { __half2 h; unsigned u; } x; x.h = h; return x.u;
}
__device__ __forceinline__ __half2 u2h(unsigned u) {
    union { unsigned u; __half2 h; } x; x.u = u; return x.h;
}
__device__ __forceinline__ float u_lo(unsigned u) {
    return __half2float(__low2half(u2h(u)));
}
__device__ __forceinline__ float u_hi(unsigned u) {
    return __half2float(__high2half(u2h(u)));
}

#if __has_builtin(__builtin_amdgcn_fdot2)
__device__ __forceinline__ float fdot2u(unsigned a, unsigned b, float c) {
    union { unsigned u; h2_t h; } ua, ub;
    ua.u = a; ub.u = b;
    return __builtin_amdgcn_fdot2(ua.h, ub.h, c, false);
}
#else
__device__ __forceinline__ float fdot2u(unsigned a, unsigned b, float c) {
    return c + u_lo(a) * u_lo(b) + u_hi(a) * u_hi(b);
}
#endif

__global__ __launch_bounds__(256) void usm_fused_kernel(
    const float* __restrict__ img, const float* __restrict__ feat,
    float* __restrict__ out, float* __restrict__ out_param)
{
    __shared__ __half tileA[PT][TA_LD];   // 88x104 f16 = 17.9 KB
    __shared__ __half tmpB[PT][TB_LD];    // 88x72  f16 = 12.4 KB

    // ---- bijective XCD swizzle: XCD k owns new-flat range [k*384,(k+1)*384) ----
    const int bid  = blockIdx.x + 8 * blockIdx.y + 64 * blockIdx.z;   // 0..3071
    const int swz  = (bid & 7) * 384 + (bid >> 3);
    const int bx   = swz & 7;
    const int by   = (swz >> 3) & 7;
    const int zc   = swz >> 6;

    const int tid = threadIdx.x;
    const int tx0 = bx * TILE, ty0 = by * TILE;
    const int b   = zc / 3;
    const float param = (tanhf(feat[b * 8]) * 0.5f + 0.5f) * 5.0f;
    const float* __restrict__ src = img + (size_t)zc * PLANE;
    const bool xedge = (bx == 0) || (bx == 7);

    // dot2 weight pairs (H)
    unsigned W2[12];
#pragma unroll
    for (int m = 0; m < 12; ++m)
        W2[m] = h2u(__floats2half2_rn(GW[2 * m], GW[2 * m + 1]));
    const unsigned WE = h2u(__floats2half2_rn(GW[24], 0.f));
    const unsigned WO = h2u(__floats2half2_rn(0.f, GW[24]));

    // broadcast weight pairs (V, packed f16)
    __half2 GWh2[KS];
#pragma unroll
    for (int k = 0; k < KS; ++k)
        GWh2[k] = __floats2half2_rn(GW[k], GW[k]);

    // ---- Stage 88x88 padded tile as f16: 968 slots ----
#pragma unroll
    for (int it = 0; it < 4; ++it) {
        const int li = tid + it * 256;
        if (it < 3 || li < N_STAGE) {
            const int py = li / 11, s = li - py * 11;
            const int gy = reflect512(ty0 - RADIUS + py);
            const float* __restrict__ rowp = src + (size_t)gy * IMG_W;
            const int gx = tx0 - RADIUS + s * 8;
            float4 va, vb;
            if (!xedge) {
                va = *(const float4*)(rowp + gx);
                vb = *(const float4*)(rowp + gx + 4);
            } else {
                va.x = rowp[reflect512(gx)];     va.y = rowp[reflect512(gx + 1)];
                va.z = rowp[reflect512(gx + 2)]; va.w = rowp[reflect512(gx + 3)];
                vb.x = rowp[reflect512(gx + 4)]; vb.y = rowp[reflect512(gx + 5)];
                vb.z = rowp[reflect512(gx + 6)]; vb.w = rowp[reflect512(gx + 7)];
            }
            uint4 pk;
            pk.x = h2u(__floats2half2_rn(va.x, va.y));
            pk.y = h2u(__floats2half2_rn(va.z, va.w));
            pk.z = h2u(__floats2half2_rn(vb.x, vb.y));
            pk.w = h2u(__floats2half2_rn(vb.z, vb.w));
            *(uint4*)&tileA[py][s * 8] = pk;
        }
    }
    __syncthreads();

    // ---- Horizontal via dot2: 704 slots ----
#pragma unroll
    for (int it = 0; it < 3; ++it) {
        const int li = tid + it * 256;
        if (it < 2 || li < N_H) {
            const int py = li >> 3, g = li & 7;
            const uint4 qa = *(const uint4*)&tileA[py][g * 8];
            const uint4 qb = *(const uint4*)&tileA[py][g * 8 + 8];
            const uint4 qc = *(const uint4*)&tileA[py][g * 8 + 16];
            const uint4 qd = *(const uint4*)&tileA[py][g * 8 + 24];

            unsigned P[16] = { qa.x, qa.y, qa.z, qa.w, qb.x, qb.y, qb.z, qb.w,
                               qc.x, qc.y, qc.z, qc.w, qd.x, qd.y, qd.z, qd.w };
            unsigned S[15];
#pragma unroll
            for (int i = 0; i < 15; ++i)
                S[i] = __builtin_amdgcn_alignbit(P[i + 1], P[i], 16);

            float acc[8];
#pragma unroll
            for (int h = 0; h < 4; ++h) {               // even outputs
                float a = 0.f;
#pragma unroll
                for (int m = 0; m < 12; ++m) a = fdot2u(P[h + m], W2[m], a);
                acc[2 * h] = fdot2u(P[h + 12], WE, a);
            }
#pragma unroll
            for (int h = 0; h < 4; ++h) {               // odd outputs
                float a = 0.f;
#pragma unroll
                for (int m = 0; m < 12; ++m) a = fdot2u(S[h + m], W2[m], a);
                acc[2 * h + 1] = fdot2u(P[h + 12], WO, a);
            }

            uint4 pk;
            pk.x = h2u(__floats2half2_rn(acc[0], acc[1]));
            pk.y = h2u(__floats2half2_rn(acc[2], acc[3]));
            pk.z = h2u(__floats2half2_rn(acc[4], acc[5]));
            pk.w = h2u(__floats2half2_rn(acc[6], acc[7]));
            *(uint4*)&tmpB[py][g * 8] = pk;
        }
    }
    __syncthreads();

    // ---- Vertical (packed f16) + epilogue: 4x4 micro-tile per thread ----
    const int tx4 = (tid & 15) * 4, ry0 = (tid >> 4) * 4;

    __half2 aP0[4], aP1[4];                    // rows d=0..3, col-pairs (x,x+1),(x+2,x+3)
#pragma unroll
    for (int d = 0; d < 4; ++d) { aP0[d] = __half2(0, 0); aP1[d] = __half2(0, 0); }

#pragma unroll
    for (int k = 0; k < KS + 3; ++k) {         // 28 b64 row reads
        const uint2 rd = *(const uint2*)&tmpB[ry0 + k][tx4];
        const __half2 p0 = u2h(rd.x), p1 = u2h(rd.y);
#pragma unroll
        for (int d = 0; d < 4; ++d) {
            const int kk = k - d;
            if (kk >= 0 && kk < KS) {
                aP0[d] = __hfma2(GWh2[kk], p0, aP0[d]);
                aP1[d] = __hfma2(GWh2[kk], p1, aP1[d]);
            }
        }
    }

    float* __restrict__ dst = out + (size_t)zc * PLANE;
#pragma unroll
    for (int d = 0; d < 4; ++d) {
        const int oy = ty0 + ry0 + d;
        // center from tileA (f16, LDS) -- no global read
        const uint2 cv = *(const uint2*)&tileA[ry0 + d + RADIUS][tx4 + RADIUS];
        const float v0 = u_lo(cv.x), v1 = u_hi(cv.x), v2 = u_lo(cv.y), v3 = u_hi(cv.y);
        const float b0 = __half2float(__low2half(aP0[d])), b1 = __half2float(__high2half(aP0[d]));
        const float b2 = __half2float(__low2half(aP1[d])), b3 = __half2float(__high2half(aP1[d]));
        float4 o;
        o.x = v0 + param * (v0 - b0);
        o.y = v1 + param * (v1 - b1);
        o.z = v2 + param * (v2 - b2);
        o.w = v3 + param * (v3 - b3);
        *(float4*)(dst + (size_t)oy * IMG_W + tx0 + tx4) = o;
    }

    if (tid == 0 && bx == 0 && by == 0 && (zc - b * 3) == 0)
        out_param[b] = param;
}

extern "C" void kernel_launch(void* const* d_in, const int* in_sizes, int n_in,
                              void* d_out, int out_size, void* d_ws, size_t ws_size,
                              hipStream_t stream) {
    const float* img  = (const float*)d_in[0];
    const float* feat = (const float*)d_in[1];
    float* out       = (float*)d_out;
    float* out_param = (float*)d_out + (size_t)NPLANE * PLANE;

    usm_fused_kernel<<<dim3(8, 8, NPLANE), 256, 0, stream>>>(img, feat, out, out_param);
}